// Round 6
// baseline (59.535 us; speedup 1.0000x reference)
//
#include <hip/hip_runtime.h>
#include <math.h>

// Problem constants (from reference setup_inputs)
#define NB      32      // batch
#define NKV     8       // kv heads
#define NQ      32      // query heads
#define GQ      4       // GQA group size = NQ/NKV
#define DH      128     // head dim
#define TPP     16      // tokens per page
#define PPS     128     // pages per slot
#define NPAGES  4096    // total pages
#define NSPLIT  16      // S-splits per (b,kv)
#define NBK     (NB*NKV)        // 256 (b,kv) pairs
#define PAGE_F  (TPP*DH)        // floats per page = 2048
#define PART_F  (GQ*DH + 2*GQ)  // partial size: o[4][128] + m[4] + l[4] = 520

// ---------------------------------------------------------------------------
// Kernel 1: barrier-free streaming paged attention partial.
// Block = (b, kv, sp). Each 16-lane group owns token slot `grp` of every
// page p = sp, sp+NSPLIT, ... with its OWN in-register online softmax.
// Lane->d mapping is LOAD-CONTIGUOUS: lane l16 covers floats
// [l16*4, l16*4+4) and [64+l16*4, 64+l16*4+4), so each dwordx4 load
// instruction is 16 lanes x 16B contiguous (full 64B cachelines), halving
// TA/TCP transactions vs the previous 32B-strided mapping.
// ---------------------------------------------------------------------------
__global__ __launch_bounds__(256) void pa_partial(
    const float* __restrict__ query,
    const float* __restrict__ key_pages,
    const float* __restrict__ value_pages,
    const int*   __restrict__ page_map,
    const int*   __restrict__ seq_lengths,
    float*       __restrict__ ws)
{
    const int blk = blockIdx.x;          // (b*NKV + kv)*NSPLIT + sp
    const int sp  = blk & (NSPLIT - 1);
    const int bk  = blk >> 4;            // NSPLIT = 16
    const int kv  = bk & (NKV - 1);
    const int b   = bk >> 3;
    const int tid = threadIdx.x;

    const int seq     = seq_lengths[b];
    const int n_pages = (seq + TPP - 1) / TPP;
    if (sp >= n_pages) return;           // combine kernel skips inactive splits

    const int grp = tid >> 4;            // token slot 0..15 within a page
    const int l16 = tid & 15;            // lane within token group
    const int c0  = l16 * 4;             // chunk 0: floats [c0, c0+4)
    const int c1  = 64 + l16 * 4;        // chunk 1: floats [c1, c1+4)

    // Q fragments (d-slices of all 4 group heads, same mapping as K)
    float qreg[GQ][8];
    #pragma unroll
    for (int g = 0; g < GQ; ++g) {
        const float* qb = query + (size_t)((b * NQ + kv * GQ + g) * DH);
        const float4 a = *(const float4*)(qb + c0);
        const float4 c = *(const float4*)(qb + c1);
        qreg[g][0] = a.x; qreg[g][1] = a.y; qreg[g][2] = a.z; qreg[g][3] = a.w;
        qreg[g][4] = c.x; qreg[g][5] = c.y; qreg[g][6] = c.z; qreg[g][7] = c.w;
    }

    const float* kbase = key_pages   + (size_t)kv * NPAGES * PAGE_F;
    const float* vbase = value_pages + (size_t)kv * NPAGES * PAGE_F;
    const int*   pmap  = page_map + b * PPS;

    // per-group online softmax state (finite init keeps masked-only groups
    // NaN-free; their l stays 0 and the merge weight underflows to 0)
    float m[GQ] = {-1e30f, -1e30f, -1e30f, -1e30f};
    float l[GQ] = {0.f, 0.f, 0.f, 0.f};
    float acc[GQ][8] = {};

    // register staging: current page's K,V row-slices (64 B/thread)
    float4 ck0, ck1, cv0, cv1;
    {
        const size_t ro = (size_t)pmap[sp] * PAGE_F + grp * DH;
        ck0 = *(const float4*)(kbase + ro + c0);
        ck1 = *(const float4*)(kbase + ro + c1);
        cv0 = *(const float4*)(vbase + ro + c0);
        cv1 = *(const float4*)(vbase + ro + c1);
    }

    for (int p = sp; p < n_pages; p += NSPLIT) {
        // issue next page's loads first; they fly during this page's compute
        float4 nk0, nk1, nv0, nv1;
        const int pn = p + NSPLIT;
        if (pn < n_pages) {
            const size_t ro = (size_t)pmap[pn] * PAGE_F + grp * DH;
            nk0 = *(const float4*)(kbase + ro + c0);
            nk1 = *(const float4*)(kbase + ro + c1);
            nv0 = *(const float4*)(vbase + ro + c0);
            nv1 = *(const float4*)(vbase + ro + c1);
        }

        // ---- scores: s[g] = q[g] . K[grp]  (reduce across 16 lanes) ----
        const float kx[8] = {ck0.x, ck0.y, ck0.z, ck0.w, ck1.x, ck1.y, ck1.z, ck1.w};
        float s[GQ];
        #pragma unroll
        for (int g = 0; g < GQ; ++g) {
            float t = qreg[g][0]*kx[0] + qreg[g][1]*kx[1] + qreg[g][2]*kx[2] + qreg[g][3]*kx[3]
                    + qreg[g][4]*kx[4] + qreg[g][5]*kx[5] + qreg[g][6]*kx[6] + qreg[g][7]*kx[7];
            #pragma unroll
            for (int off = 8; off >= 1; off >>= 1) t += __shfl_xor(t, off);
            s[g] = t;
        }

        const bool valid = (p * TPP + grp) < seq;
        const float vx[8] = {cv0.x, cv0.y, cv0.z, cv0.w, cv1.x, cv1.y, cv1.z, cv1.w};

        // ---- per-group online softmax update (single token) ----
        #pragma unroll
        for (int g = 0; g < GQ; ++g) {
            const float mn = fmaxf(m[g], s[g]);
            float pc = __expf(s[g] - mn);
            pc = valid ? pc : 0.f;
            const float sc = __expf(m[g] - mn);
            m[g] = mn;
            l[g] = l[g] * sc + pc;
            #pragma unroll
            for (int j = 0; j < 8; ++j)
                acc[g][j] = acc[g][j] * sc + pc * vx[j];
        }

        ck0 = nk0; ck1 = nk1; cv0 = nv0; cv1 = nv1;   // SSA rename, free
    }

    // ---- block-level merge of the 16 group partials via LDS ----
    __shared__ float s_acc[16][GQ][DH];   // 32 KB
    __shared__ float s_m[16][GQ];
    __shared__ float s_l[16][GQ];

    #pragma unroll
    for (int g = 0; g < GQ; ++g) {
        *(float4*)&s_acc[grp][g][c0] = make_float4(acc[g][0], acc[g][1], acc[g][2], acc[g][3]);
        *(float4*)&s_acc[grp][g][c1] = make_float4(acc[g][4], acc[g][5], acc[g][6], acc[g][7]);
    }
    if (l16 == 0) {
        #pragma unroll
        for (int g = 0; g < GQ; ++g) { s_m[grp][g] = m[g]; s_l[grp][g] = l[g]; }
    }
    __syncthreads();

    // remap: thread -> (gA, d) and (gB, d)
    const int d  = tid & 127;
    const int gA = tid >> 7;     // 0 or 1
    const int gB = gA + 2;       // 2 or 3

    float MA = -1e30f, MB = -1e30f;
    #pragma unroll
    for (int i = 0; i < 16; ++i) {
        MA = fmaxf(MA, s_m[i][gA]);
        MB = fmaxf(MB, s_m[i][gB]);
    }
    float LA = 0.f, LB = 0.f, oA = 0.f, oB = 0.f;
    #pragma unroll
    for (int i = 0; i < 16; ++i) {
        const float eA = __expf(s_m[i][gA] - MA);
        const float eB = __expf(s_m[i][gB] - MB);
        LA += s_l[i][gA] * eA;
        LB += s_l[i][gB] * eB;
        oA += s_acc[i][gA][d] * eA;
        oB += s_acc[i][gB][d] * eB;
    }

    // ---- write partial (o unnormalized, m, l); ws layout unchanged ----
    float* base = ws + (size_t)(bk * NSPLIT + sp) * PART_F;
    base[gA * DH + d] = oA;
    base[gB * DH + d] = oB;
    if (d == 0) {  // tid 0 writes g0,g2 ; tid 128 writes g1,g3
        base[GQ * DH + gA]      = MA;
        base[GQ * DH + GQ + gA] = LA;
        base[GQ * DH + gB]      = MB;
        base[GQ * DH + GQ + gB] = LB;
    }
}

// ---------------------------------------------------------------------------
// Kernel 2: combine the <=NSPLIT split partials per (b, kv), write output.
// ---------------------------------------------------------------------------
__global__ __launch_bounds__(256) void pa_combine(
    const float* __restrict__ ws,
    const int*   __restrict__ seq_lengths,
    float*       __restrict__ out)
{
    const int blk = blockIdx.x;    // b*NKV + kv
    const int b   = blk >> 3;
    const int kv  = blk & 7;
    const int tid = threadIdx.x;
    const int d   = tid & 127;
    const int gA  = tid >> 7;
    const int gB  = gA + 2;

    const int seq     = seq_lengths[b];
    const int n_pages = (seq + TPP - 1) / TPP;
    const int ns      = (n_pages < NSPLIT) ? n_pages : NSPLIT;

    const float* base0 = ws + (size_t)blk * NSPLIT * PART_F;

    float MA = -1e30f, MB = -1e30f;
    for (int si = 0; si < ns; ++si) {
        const float* p = base0 + si * PART_F;
        MA = fmaxf(MA, p[GQ * DH + gA]);
        MB = fmaxf(MB, p[GQ * DH + gB]);
    }

    float LA = 0.f, LB = 0.f, oA = 0.f, oB = 0.f;
    for (int si = 0; si < ns; ++si) {
        const float* p = base0 + si * PART_F;
        const float eA = __expf(p[GQ * DH + gA] - MA);
        const float eB = __expf(p[GQ * DH + gB] - MB);
        LA += p[GQ * DH + GQ + gA] * eA;
        LB += p[GQ * DH + GQ + gB] * eB;
        oA += p[gA * DH + d] * eA;
        oB += p[gB * DH + d] * eB;
    }

    float* ob = out + (size_t)(b * NQ + kv * GQ) * DH;
    ob[gA * DH + d] = oA / LA;
    ob[gB * DH + d] = oB / LB;
}

// ---------------------------------------------------------------------------
extern "C" void kernel_launch(void* const* d_in, const int* in_sizes, int n_in,
                              void* d_out, int out_size, void* d_ws, size_t ws_size,
                              hipStream_t stream)
{
    const float* query       = (const float*)d_in[0];
    const float* key_pages   = (const float*)d_in[1];
    const float* value_pages = (const float*)d_in[2];
    const int*   page_map    = (const int*)d_in[3];
    const int*   seq_lengths = (const int*)d_in[4];
    float*       out         = (float*)d_out;
    float*       ws          = (float*)d_ws;

    // ws usage: NBK*NSPLIT * PART_F floats = 4096 * 520 * 4B ~= 8.5 MB
    pa_partial<<<NBK * NSPLIT, 256, 0, stream>>>(
        query, key_pages, value_pages, page_map, seq_lengths, ws);
    pa_combine<<<NBK, 256, 0, stream>>>(ws, seq_lengths, out);
}